// Round 2
// baseline (445.806 us; speedup 1.0000x reference)
//
#include <hip/hip_runtime.h>
#include <math.h>

#define NEG_INF (-INFINITY)

typedef float f4 __attribute__((ext_vector_type(4)));

static __device__ __forceinline__ f4 ld4(const float* p) {
    return *(const f4*)p;
}

// out[j] = max(X[j], O[j], Y[j], X[j+1], Y[j+1])
// (own-coset rows X=row i, Y=row i+1; other-coset row O=row i)
static __device__ __forceinline__ f4 pool_a(f4 X, f4 Y, f4 O, float Xe, float Ye) {
    f4 r;
    r.x = fmaxf(fmaxf(fmaxf(X.x, O.x), fmaxf(Y.x, X.y)), Y.y);
    r.y = fmaxf(fmaxf(fmaxf(X.y, O.y), fmaxf(Y.y, X.z)), Y.z);
    r.z = fmaxf(fmaxf(fmaxf(X.z, O.z), fmaxf(Y.z, X.w)), Y.w);
    r.w = fmaxf(fmaxf(fmaxf(X.w, O.w), fmaxf(Y.w, Xe)), Ye);
    return r;
}

// out[j] = max(X[j], Y[j], X[j+1], Y[j+1], Wv[j+1])
// (own-coset rows X=row i, Y=row i+1; other-coset row Wv=row i+1)
static __device__ __forceinline__ f4 pool_b(f4 X, f4 Y, f4 Wv, float Xe, float Ye, float We) {
    f4 r;
    r.x = fmaxf(fmaxf(fmaxf(X.x, Y.x), fmaxf(X.y, Y.y)), Wv.y);
    r.y = fmaxf(fmaxf(fmaxf(X.y, Y.y), fmaxf(X.z, Y.z)), Wv.z);
    r.z = fmaxf(fmaxf(fmaxf(X.z, Y.z), fmaxf(X.w, Y.w)), Wv.w);
    r.w = fmaxf(fmaxf(fmaxf(X.w, Y.w), fmaxf(Xe, Ye)), We);
    return r;
}

// out0[i][j] = max(c0[i][j], c1[i][j], c0[i+1][j], c0[i][j+1], c0[i+1][j+1])
// out1[i][j] = max(c1[i][j], c1[i+1][j], c1[i][j+1], c1[i+1][j+1], c0[i+1][j+1])
//
// Block tile: 64 j-groups (x) x 4 row-pairs (y) = 8 rows per block.
// Block order: row-group innermost (adjacent blocks share a boundary row),
// XCD-chunk swizzle keeps adjacent blocks on the same XCD -> boundary re-read
// is a local-L2 hit instead of a cross-XCD L3 round-trip.
__global__ __launch_bounds__(256) void quincunx_pool2d_kernel(
    const float* __restrict__ c0, const float* __restrict__ c1,
    float* __restrict__ out, long N /* elems per coset */)
{
    const int H = 512, W = 512;

    // Bijective XCD swizzle: nblocks % 8 == 0 (16384 blocks).
    const int nb = gridDim.x;
    const int chunk = nb >> 3;                 // blocks per XCD chunk
    const int bid = blockIdx.x;
    const int swz = (bid & 7) * chunk + (bid >> 3);

    // Decompose: swz = p * 128 + jh * 64 + rbg   (rbg innermost)
    const int rbg = swz & 63;                  // row-group: 8 rows (4 row-pairs)
    const int jh  = (swz >> 6) & 1;            // which half of the row (j)
    const long p  = swz >> 7;                  // image (B*C)

    const int tid = threadIdx.x;
    const int jl  = tid & 63;                  // j-group within half-row
    const int rpl = tid >> 6;                  // row-pair within row-group (0..3)

    const int jg = (jh << 6) + jl;             // global j-group (0..127)
    const int rp = (rbg << 2) + rpl;           // global row-pair (0..255)
    const int i  = rp << 1;
    const int j4 = jg << 2;

    const long base = p * (long)(H * W) + (long)i * W + j4;

    const f4 ninf = {NEG_INF, NEG_INF, NEG_INF, NEG_INF};

    // Rows i, i+1 always valid; row i+2 -inf-padded at the bottom edge.
    f4 a0 = ld4(c0 + base),     b0 = ld4(c1 + base);
    f4 a1 = ld4(c0 + base + W), b1 = ld4(c1 + base + W);
    f4 a2 = ninf, b2 = ninf;
    const bool hasI2 = (rp != 255);            // wave-uniform (wave spans j only)
    if (hasI2) {
        a2 = ld4(c0 + base + 2 * W);
        b2 = ld4(c1 + base + 2 * W);
    }

    // j+1 spill-over element at j4+4 (same cache line as neighbor lane's vector).
    const bool hasJ = (jg != 127);
    float a0e = hasJ ? c0[base + 4] : NEG_INF;
    float b0e = hasJ ? c1[base + 4] : NEG_INF;
    float a1e = hasJ ? c0[base + W + 4] : NEG_INF;
    float b1e = hasJ ? c1[base + W + 4] : NEG_INF;
    float a2e = (hasJ && hasI2) ? c0[base + 2 * W + 4] : NEG_INF;
    float b2e = (hasJ && hasI2) ? c1[base + 2 * W + 4] : NEG_INF;

    f4 o0a = pool_a(a0, a1, b0, a0e, a1e);       // out0 row i
    f4 o1a = pool_b(b0, b1, a1, b0e, b1e, a1e);  // out1 row i
    f4 o0b = pool_a(a1, a2, b1, a1e, a2e);       // out0 row i+1
    f4 o1b = pool_b(b1, b2, a2, b1e, b2e, a2e);  // out1 row i+1

    *(f4*)(out + base)         = o0a;
    *(f4*)(out + base + W)     = o0b;
    *(f4*)(out + N + base)     = o1a;
    *(f4*)(out + N + base + W) = o1b;
}

extern "C" void kernel_launch(void* const* d_in, const int* in_sizes, int n_in,
                              void* d_out, int out_size, void* d_ws, size_t ws_size,
                              hipStream_t stream) {
    const float* c0 = (const float*)d_in[0];
    const float* c1 = (const float*)d_in[1];
    float* out = (float*)d_out;

    const int H = 512, W = 512;
    long N = (long)in_sizes[0];                // elements per coset = 4*32*512*512
    long P = N / (long)(H * W);                // images (B*C) = 128
    // 128 blocks per image: 2 j-halves x 64 row-groups
    int blocks = (int)(P * 128);
    int threads = 256;

    quincunx_pool2d_kernel<<<blocks, threads, 0, stream>>>(c0, c1, out, N);
}

// Round 3
// 428.118 us; speedup vs baseline: 1.0413x; 1.0413x over previous
//
#include <hip/hip_runtime.h>
#include <math.h>

#define NEG_INF (-INFINITY)

// out0[i][j] = max(c0[i][j], c1[i][j], c0[i+1][j], c0[i][j+1], c0[i+1][j+1])
// out1[i][j] = max(c1[i][j], c1[i+1][j], c1[i][j+1], c1[i+1][j+1], c0[i+1][j+1])
// One thread computes 4 contiguous j for BOTH outputs (shared loads).
//
// NOTE (session journal): this simple 1-row-per-thread form is the measured
// optimum. Round-1 (2-row register blocking + nontemporal stores, 436 µs) and
// round-2 (2D block tile + bijective XCD swizzle, 446 µs) both regressed vs
// this kernel's 430 µs. The row-overlap re-reads are fully absorbed by the
// 256 MiB L3 (input = 268 MB), so locality restructuring has nothing to win;
// kernel dispatch ≈ 101 µs ≈ 84% of the measured 6.29 TB/s mixed R/W ceiling
// (537 MB mandatory traffic → 85 µs floor). Keep it simple and streaming.
__global__ __launch_bounds__(256) void quincunx_pool_kernel(
    const float* __restrict__ c0, const float* __restrict__ c1,
    float* __restrict__ out, long N /* elems per coset */)
{
    const int H = 512, W = 512;
    const int wq = W >> 2;  // 128 column-groups per row

    long idx = (long)blockIdx.x * blockDim.x + threadIdx.x;
    int j4 = (int)(idx % wq) * 4;
    int i  = (int)((idx / wq) % H);
    long p = idx / ((long)wq * H);

    long base = p * (long)(H * W) + (long)i * W + j4;

    // Row i of both cosets (always in range).
    float4 a0 = *(const float4*)(c0 + base);
    float4 b0 = *(const float4*)(c1 + base);

    // Row i+1, -inf padded at the bottom edge.
    const bool hasI1 = (i + 1) < H;
    float4 a1, b1;
    if (hasI1) {
        a1 = *(const float4*)(c0 + base + W);
        b1 = *(const float4*)(c1 + base + W);
    } else {
        a1 = make_float4(NEG_INF, NEG_INF, NEG_INF, NEG_INF);
        b1 = a1;
    }

    // j+1 spill-over element at j4+4 (only needed for lane 3 of the vector).
    const bool hasJ = (j4 + 4) < W;
    float a0e = hasJ ? c0[base + 4] : NEG_INF;
    float b0e = hasJ ? c1[base + 4] : NEG_INF;
    float a1e = (hasJ && hasI1) ? c0[base + W + 4] : NEG_INF;
    float b1e = (hasJ && hasI1) ? c1[base + W + 4] : NEG_INF;

    float4 o0, o1;
    // element 0 (j = j4):  j+1 values are the .y components
    o0.x = fmaxf(fmaxf(fmaxf(a0.x, b0.x), fmaxf(a1.x, a0.y)), a1.y);
    o1.x = fmaxf(fmaxf(fmaxf(b0.x, b1.x), fmaxf(b0.y, b1.y)), a1.y);
    // element 1
    o0.y = fmaxf(fmaxf(fmaxf(a0.y, b0.y), fmaxf(a1.y, a0.z)), a1.z);
    o1.y = fmaxf(fmaxf(fmaxf(b0.y, b1.y), fmaxf(b0.z, b1.z)), a1.z);
    // element 2
    o0.z = fmaxf(fmaxf(fmaxf(a0.z, b0.z), fmaxf(a1.z, a0.w)), a1.w);
    o1.z = fmaxf(fmaxf(fmaxf(b0.z, b1.z), fmaxf(b0.w, b1.w)), a1.w);
    // element 3: j+1 values come from the edge loads
    o0.w = fmaxf(fmaxf(fmaxf(a0.w, b0.w), fmaxf(a1.w, a0e)), a1e);
    o1.w = fmaxf(fmaxf(fmaxf(b0.w, b1.w), fmaxf(b0e, b1e)), a1e);

    *(float4*)(out + base)     = o0;
    *(float4*)(out + N + base) = o1;
}

extern "C" void kernel_launch(void* const* d_in, const int* in_sizes, int n_in,
                              void* d_out, int out_size, void* d_ws, size_t ws_size,
                              hipStream_t stream) {
    const float* c0 = (const float*)d_in[0];
    const float* c1 = (const float*)d_in[1];
    float* out = (float*)d_out;

    long N = (long)in_sizes[0];              // elements per coset = 4*32*512*512
    long total_threads = N / 4;              // one thread per 4 columns
    int threads = 256;
    int blocks = (int)((total_threads + threads - 1) / threads);

    quincunx_pool_kernel<<<blocks, threads, 0, stream>>>(c0, c1, out, N);
}